// Round 1
// baseline (24384.196 us; speedup 1.0000x reference)
//
#include <hip/hip_runtime.h>
#include <hip/hip_bf16.h>
#include <math.h>

#define N_   8192
#define P_   64
#define C_   128
#define M_   4096
#define MW_  (M_ * P_)     // 262144
#define A_   131072
#define BL_  65536
#define NROWS_ (N_ * P_)   // 524288

__device__ __forceinline__ float wave_sum(float v) {
#pragma unroll
  for (int o = 32; o > 0; o >>= 1) v += __shfl_xor(v, o, 64);
  return v;
}
__device__ __forceinline__ float wave_max(float v) {
#pragma unroll
  for (int o = 32; o > 0; o >>= 1) v = fmaxf(v, __shfl_xor(v, o, 64));
  return v;
}

// ---------------- flags ----------------
__global__ __launch_bounds__(256) void k_set8(unsigned char* p, int n) {
  int i = blockIdx.x * 256 + threadIdx.x;
  if (i < n) p[i] = 0;
}
__global__ __launch_bounds__(256) void k_scatter8(unsigned char* p, const int* __restrict__ idx,
                                                  unsigned char v, int n) {
  int i = blockIdx.x * 256 + threadIdx.x;
  if (i < n) p[idx[i]] = v;
}

// ---------------- LN1 over all rows -> out ----------------
__global__ __launch_bounds__(256) void k_ln_all(const float* __restrict__ x,
                                                const float* __restrict__ w,
                                                const float* __restrict__ b,
                                                float* __restrict__ out) {
  int row = blockIdx.x * 4 + (threadIdx.x >> 6);
  int lane = threadIdx.x & 63;
  float2 xv = ((const float2*)(x + (size_t)row * 128))[lane];
  float mean = wave_sum(xv.x + xv.y) * (1.0f / 128.0f);
  float d0 = xv.x - mean, d1 = xv.y - mean;
  float inv = rsqrtf(wave_sum(d0 * d0 + d1 * d1) * (1.0f / 128.0f) + 1e-6f);
  float2 wv = ((const float2*)w)[lane];
  float2 bv = ((const float2*)b)[lane];
  float2 o2;
  o2.x = d0 * inv * wv.x + bv.x;
  o2.y = d1 * inv * wv.y + bv.y;
  ((float2*)(out + (size_t)row * 128))[lane] = o2;
}

// ---------------- attention: one block per partition ----------------
__global__ __launch_bounds__(256) void k_attn(
    const float* __restrict__ x, const int* __restrict__ iw,
    const int* __restrict__ ip, const unsigned char* __restrict__ flags,
    const float* __restrict__ ln1w, const float* __restrict__ ln1b,
    const float* __restrict__ qkvw, const float* __restrict__ qkvb,
    const float* __restrict__ projw, const float* __restrict__ projb,
    float* __restrict__ out) {
  __shared__ __hip_bfloat16 Xs[64][128];   // 16 KB
  __shared__ float Qb[64][33];             // 8.25 KB (pad 33 -> conflict-free)
  __shared__ float Kb[64][33];
  __shared__ float Vb[64][33];
  __shared__ float Sb[64][64];             // 16 KB
  __shared__ int srow[64];
  __shared__ unsigned char fl[64];

  const int tid = threadIdx.x;
  const int w = tid >> 6, lane = tid & 63;
  const int m = blockIdx.x;

  // ---- gather 64 rows from pristine x, LN1 (+re-LN if asy), store bf16 ----
  for (int r = w; r < 64; r += 4) {
    int s = ip[(m << 6) + r];
    unsigned char f = flags[s];
    int wr = iw[s >> 6] * 64 + (s & 63);
    if (lane == 0) { srow[r] = wr; fl[r] = f; }
    float2 xv = ((const float2*)(x + (size_t)wr * 128))[lane];
    float mean = wave_sum(xv.x + xv.y) * (1.0f / 128.0f);
    float d0 = xv.x - mean, d1 = xv.y - mean;
    float inv = rsqrtf(wave_sum(d0 * d0 + d1 * d1) * (1.0f / 128.0f) + 1e-6f);
    float w0 = ln1w[2 * lane], w1 = ln1w[2 * lane + 1];
    float b0 = ln1b[2 * lane], b1 = ln1b[2 * lane + 1];
    float y0 = d0 * inv * w0 + b0, y1 = d1 * inv * w1 + b1;
    if (f == 1) {  // asy: second LN (wave-uniform branch)
      mean = wave_sum(y0 + y1) * (1.0f / 128.0f);
      d0 = y0 - mean; d1 = y1 - mean;
      inv = rsqrtf(wave_sum(d0 * d0 + d1 * d1) * (1.0f / 128.0f) + 1e-6f);
      y0 = d0 * inv * w0 + b0; y1 = d1 * inv * w1 + b1;
    }
    Xs[r][2 * lane] = __float2bfloat16(y0);
    Xs[r][2 * lane + 1] = __float2bfloat16(y1);
  }
  __syncthreads();

  float pacc[32];
#pragma unroll
  for (int i = 0; i < 32; ++i) pacc[i] = 0.0f;

  const float scale = 0.17677669529663687f;  // 1/sqrt(32)

  for (int h = 0; h < 4; ++h) {
    // ---- QKV: 64 rows x 96 cols, dot length 128 ----
    for (int it = 0; it < 24; ++it) {
      int idx = tid + (it << 8);
      int r = idx / 96, cc = idx - r * 96;
      int wcol = h * 96 + cc;
      float acc = qkvb[wcol];
#pragma unroll 8
      for (int c = 0; c < 128; ++c)
        acc += __bfloat162float(Xs[r][c]) * qkvw[c * 384 + wcol];
      if (cc < 32) Qb[r][cc] = acc;
      else if (cc < 64) Kb[r][cc - 32] = acc;
      else Vb[r][cc - 64] = acc;
    }
    __syncthreads();

    // ---- scores + blocked mask ----
    for (int it = 0; it < 16; ++it) {
      int idx = tid + (it << 8);
      int qr = idx >> 6, kr = idx & 63;
      float acc = 0.0f;
#pragma unroll
      for (int d = 0; d < 32; ++d) acc += Qb[qr][d] * Kb[kr][d];
      Sb[qr][kr] = (fl[kr] == 2) ? -10000.0f : acc * scale;
    }
    __syncthreads();

    // ---- softmax: one wave per row ----
    for (int r = w; r < 64; r += 4) {
      float v = Sb[r][lane];
      float mx = wave_max(v);
      float e = __expf(v - mx);
      float sm = wave_sum(e);
      Sb[r][lane] = e / sm;
    }
    __syncthreads();

    // ---- O = P @ V  (reuse Qb as O) ----
    for (int it = 0; it < 8; ++it) {
      int idx = tid + (it << 8);
      int r = idx >> 5, d = idx & 31;
      float acc = 0.0f;
#pragma unroll
      for (int kr = 0; kr < 64; ++kr) acc += Sb[r][kr] * Vb[kr][d];
      Qb[r][d] = acc;
    }
    __syncthreads();

    // ---- proj partial accumulate in registers ----
    for (int it = 0; it < 32; ++it) {
      int idx = tid + (it << 8);
      int r = idx >> 7, j = idx & 127;
      float acc = pacc[it];
#pragma unroll
      for (int d = 0; d < 32; ++d)
        acc += Qb[r][d] * projw[(h * 32 + d) * 128 + j];
      pacc[it] = acc;
    }
    __syncthreads();
  }

  // ---- write o rows to out (skip blocked; permutation => race-free) ----
  for (int it = 0; it < 32; ++it) {
    int idx = tid + (it << 8);
    int r = idx >> 7, j = idx & 127;
    if (fl[r] != 2)
      out[(size_t)srow[r] * 128 + j] = pacc[it] + projb[j];
  }
}

// ---------------- MLP path: one wave per asy row, in-place on out ----------------
__global__ __launch_bounds__(256) void k_mlp(
    const float* __restrict__ x, const int* __restrict__ iw,
    const int* __restrict__ ia,
    const float* __restrict__ ln1w, const float* __restrict__ ln1b,
    const float* __restrict__ g1,
    const float* __restrict__ ln2w, const float* __restrict__ ln2b,
    const float* __restrict__ w1, const float* __restrict__ b1,
    const float* __restrict__ w2, const float* __restrict__ b2,
    const float* __restrict__ g2,
    float* __restrict__ out) {
  __shared__ float y2s[4][128];
  __shared__ float hs[4][512];
  const int tid = threadIdx.x, w = tid >> 6, lane = tid & 63;
  const int i = blockIdx.x * 4 + w;
  int s = ia[i];
  int wr = iw[s >> 6] * 64 + (s & 63);

  // xa = LN1(LN1(x_row)) with ln1 params (row is asy by construction)
  float2 xv = ((const float2*)(x + (size_t)wr * 128))[lane];
  float mean = wave_sum(xv.x + xv.y) * (1.0f / 128.0f);
  float d0 = xv.x - mean, d1 = xv.y - mean;
  float inv = rsqrtf(wave_sum(d0 * d0 + d1 * d1) * (1.0f / 128.0f) + 1e-6f);
  float lw0 = ln1w[2 * lane], lw1 = ln1w[2 * lane + 1];
  float lb0 = ln1b[2 * lane], lb1 = ln1b[2 * lane + 1];
  float y0 = d0 * inv * lw0 + lb0, y1 = d1 * inv * lw1 + lb1;
  mean = wave_sum(y0 + y1) * (1.0f / 128.0f);
  d0 = y0 - mean; d1 = y1 - mean;
  inv = rsqrtf(wave_sum(d0 * d0 + d1 * d1) * (1.0f / 128.0f) + 1e-6f);
  float xa0 = d0 * inv * lw0 + lb0, xa1 = d1 * inv * lw1 + lb1;

  // y = xa + gamma1 * o   (o = attention output, already in out)
  float2 ov = ((const float2*)(out + (size_t)wr * 128))[lane];
  float yv0 = xa0 + g1[2 * lane] * ov.x;
  float yv1 = xa1 + g1[2 * lane + 1] * ov.y;

  // y2 = LN2(y)
  mean = wave_sum(yv0 + yv1) * (1.0f / 128.0f);
  d0 = yv0 - mean; d1 = yv1 - mean;
  inv = rsqrtf(wave_sum(d0 * d0 + d1 * d1) * (1.0f / 128.0f) + 1e-6f);
  y2s[w][2 * lane] = d0 * inv * ln2w[2 * lane] + ln2b[2 * lane];
  y2s[w][2 * lane + 1] = d1 * inv * ln2w[2 * lane + 1] + ln2b[2 * lane + 1];
  __syncthreads();

  // h = gelu_exact(y2 @ W1 + b1)
  for (int u = 0; u < 8; ++u) {
    int j = lane + (u << 6);
    float acc = b1[j];
#pragma unroll 8
    for (int c = 0; c < 128; ++c) acc += y2s[w][c] * w1[c * 512 + j];
    hs[w][j] = acc * 0.5f * (1.0f + erff(acc * 0.70710678118654752f));
  }
  __syncthreads();

  // z = h @ W2 + b2 ; final = y + gamma2 * z
  float2 bv = ((const float2*)b2)[lane];
  float a0 = bv.x, a1 = bv.y;
  for (int c = 0; c < 512; ++c) {
    float hv = hs[w][c];
    float2 wv = ((const float2*)(w2 + (size_t)c * 128))[lane];
    a0 += hv * wv.x;
    a1 += hv * wv.y;
  }
  float f0 = yv0 + g2[2 * lane] * a0;
  float f1 = yv1 + g2[2 * lane + 1] * a1;
  ((float2*)(out + (size_t)wr * 128))[lane] = make_float2(f0, f1);
}

extern "C" void kernel_launch(void* const* d_in, const int* in_sizes, int n_in,
                              void* d_out, int out_size, void* d_ws, size_t ws_size,
                              hipStream_t stream) {
  const float* x = (const float*)d_in[0];
  const int* iw = (const int*)d_in[1];
  const int* ip = (const int*)d_in[2];
  const int* ia = (const int*)d_in[3];
  const int* ib = (const int*)d_in[4];
  const float* ln1w = (const float*)d_in[7];
  const float* ln1b = (const float*)d_in[8];
  const float* qkvw = (const float*)d_in[9];
  const float* qkvb = (const float*)d_in[10];
  const float* projw = (const float*)d_in[11];
  const float* projb = (const float*)d_in[12];
  const float* g1 = (const float*)d_in[13];
  const float* ln2w = (const float*)d_in[14];
  const float* ln2b = (const float*)d_in[15];
  const float* w1 = (const float*)d_in[16];
  const float* b1 = (const float*)d_in[17];
  const float* w2 = (const float*)d_in[18];
  const float* b2 = (const float*)d_in[19];
  const float* g2 = (const float*)d_in[20];
  float* out = (float*)d_out;

  unsigned char* flags = (unsigned char*)d_ws;  // MW_ bytes

  k_set8<<<MW_ / 256, 256, 0, stream>>>(flags, MW_);
  k_scatter8<<<A_ / 256, 256, 0, stream>>>(flags, ia, 1, A_);
  k_scatter8<<<BL_ / 256, 256, 0, stream>>>(flags, ib, 2, BL_);
  k_ln_all<<<NROWS_ / 4, 256, 0, stream>>>(x, ln1w, ln1b, out);
  k_attn<<<M_, 256, 0, stream>>>(x, iw, ip, flags, ln1w, ln1b, qkvw, qkvb,
                                 projw, projb, out);
  k_mlp<<<A_ / 4, 256, 0, stream>>>(x, iw, ia, ln1w, ln1b, g1, ln2w, ln2b,
                                    w1, b1, w2, b2, g2, out);
}

// Round 2
// 3579.390 us; speedup vs baseline: 6.8124x; 6.8124x over previous
//
#include <hip/hip_runtime.h>
#include <hip/hip_bf16.h>
#include <math.h>

#define N_   8192
#define P_   64
#define C_   128
#define M_   4096
#define MW_  (M_ * P_)     // 262144
#define A_   131072
#define BL_  65536
#define NROWS_ (N_ * P_)   // 524288

typedef __attribute__((ext_vector_type(8))) __bf16 bf16x8;
typedef __attribute__((ext_vector_type(4))) float f32x4;
typedef __attribute__((ext_vector_type(2))) __bf16 bf16x2;

__device__ __forceinline__ float wave_sum(float v) {
#pragma unroll
  for (int o = 32; o > 0; o >>= 1) v += __shfl_xor(v, o, 64);
  return v;
}

// ---------------- flags ----------------
__global__ __launch_bounds__(256) void k_set8(unsigned char* p, int n) {
  int i = blockIdx.x * 256 + threadIdx.x;
  if (i < n) p[i] = 0;
}
__global__ __launch_bounds__(256) void k_scatter8(unsigned char* p, const int* __restrict__ idx,
                                                  unsigned char v, int n) {
  int i = blockIdx.x * 256 + threadIdx.x;
  if (i < n) p[idx[i]] = v;
}

// ---------------- weight prep: bf16 transposed copies into ws ----------------
__global__ __launch_bounds__(256) void k_prep(const float* __restrict__ qkvw,
                                              const float* __restrict__ projw,
                                              __bf16* __restrict__ qkvt,
                                              __bf16* __restrict__ projt) {
  int i = blockIdx.x * 256 + threadIdx.x;
  if (i < 384 * 128) {
    int col = i >> 7, row = i & 127;
    qkvt[i] = (__bf16)qkvw[row * 384 + col];   // qkvt[col][row]
  } else {
    int j = i - 384 * 128;
    int col = j >> 7, row = j & 127;
    projt[j] = (__bf16)projw[row * 128 + col]; // projt[col][row]
  }
}

// ---------------- LN1 over all rows -> out ----------------
__global__ __launch_bounds__(256) void k_ln_all(const float* __restrict__ x,
                                                const float* __restrict__ w,
                                                const float* __restrict__ b,
                                                float* __restrict__ out) {
  int row = blockIdx.x * 4 + (threadIdx.x >> 6);
  int lane = threadIdx.x & 63;
  float2 xv = ((const float2*)(x + (size_t)row * 128))[lane];
  float mean = wave_sum(xv.x + xv.y) * (1.0f / 128.0f);
  float d0 = xv.x - mean, d1 = xv.y - mean;
  float inv = rsqrtf(wave_sum(d0 * d0 + d1 * d1) * (1.0f / 128.0f) + 1e-6f);
  float2 wv = ((const float2*)w)[lane];
  float2 bv = ((const float2*)b)[lane];
  float2 o2;
  o2.x = d0 * inv * wv.x + bv.x;
  o2.y = d1 * inv * wv.y + bv.y;
  ((float2*)(out + (size_t)row * 128))[lane] = o2;
}

// ---------------- attention: one block per partition, MFMA ----------------
// LDS: Xs 64x136 bf16 (17.4KB) + 4 x per-wave scratch 7424 bf16 (59.4KB) = ~77KB
// per-wave scratch regions (elems): Q @0 (64x40), K @2560 (64x40), Vt @5120 (32x72)
//   P (64x72) reuses Q+K after S; O (64x40) reuses Q after PV.
__global__ __launch_bounds__(256) void k_attn(
    const float* __restrict__ x, const int* __restrict__ iw,
    const int* __restrict__ ip, const unsigned char* __restrict__ flags,
    const float* __restrict__ ln1w, const float* __restrict__ ln1b,
    const __bf16* __restrict__ qkvt, const float* __restrict__ qkvb,
    const __bf16* __restrict__ projt, const float* __restrict__ projb,
    float* __restrict__ out) {
  __shared__ __align__(16) __bf16 Xs[64 * 136];
  __shared__ __align__(16) __bf16 scratch[4 * 7424];
  __shared__ int srow[64];
  __shared__ unsigned char fl[64];

  const int tid = threadIdx.x;
  const int w = tid >> 6, lane = tid & 63;
  const int quad = lane >> 4, cl = lane & 15;
  const int m = blockIdx.x;

  // ---- phase 0: gather 64 rows, LN1 (+re-LN if asy), store bf16 tile ----
  for (int r = w; r < 64; r += 4) {
    int s = ip[(m << 6) + r];
    unsigned char f = flags[s];
    int wr = iw[s >> 6] * 64 + (s & 63);
    if (lane == 0) { srow[r] = wr; fl[r] = f; }
    float2 xv = ((const float2*)(x + (size_t)wr * 128))[lane];
    float mean = wave_sum(xv.x + xv.y) * (1.0f / 128.0f);
    float d0 = xv.x - mean, d1 = xv.y - mean;
    float inv = rsqrtf(wave_sum(d0 * d0 + d1 * d1) * (1.0f / 128.0f) + 1e-6f);
    float w0 = ln1w[2 * lane], w1 = ln1w[2 * lane + 1];
    float b0 = ln1b[2 * lane], b1 = ln1b[2 * lane + 1];
    float y0 = d0 * inv * w0 + b0, y1 = d1 * inv * w1 + b1;
    if (f == 1) {
      mean = wave_sum(y0 + y1) * (1.0f / 128.0f);
      d0 = y0 - mean; d1 = y1 - mean;
      inv = rsqrtf(wave_sum(d0 * d0 + d1 * d1) * (1.0f / 128.0f) + 1e-6f);
      y0 = d0 * inv * w0 + b0; y1 = d1 * inv * w1 + b1;
    }
    bf16x2 p2;
    p2[0] = (__bf16)y0; p2[1] = (__bf16)y1;
    *(bf16x2*)&Xs[r * 136 + 2 * lane] = p2;
  }
  __syncthreads();

  __bf16* wsc = scratch + w * 7424;
  __bf16* Qs  = wsc;          // [64][40]
  __bf16* Ks  = wsc + 2560;   // [64][40]
  __bf16* Vts = wsc + 5120;   // [32][72]  (Vt[d][pos])
  __bf16* Ps  = wsc;          // [64][72]  (over Q+K, after S)
  __bf16* Os  = wsc;          // [64][40]  (over Q, after PV)
  const int h = w;

  // ---- phase 1: QKV = Xs @ Wqkv_head (MFMA), write Q,K,Vt to LDS ----
  bf16x8 af[4][4];
#pragma unroll
  for (int mt = 0; mt < 4; ++mt)
#pragma unroll
    for (int kt = 0; kt < 4; ++kt)
      af[mt][kt] = *(const bf16x8*)&Xs[(mt * 16 + cl) * 136 + kt * 32 + quad * 8];

  for (int t = 0; t < 3; ++t) {
#pragma unroll
    for (int nt = 0; nt < 2; ++nt) {
      int col = h * 96 + t * 32 + nt * 16 + cl;
      bf16x8 bfr[4];
#pragma unroll
      for (int kt = 0; kt < 4; ++kt)
        bfr[kt] = *(const bf16x8*)&qkvt[(size_t)col * 128 + kt * 32 + quad * 8];
      float bias = qkvb[col];
#pragma unroll
      for (int mt = 0; mt < 4; ++mt) {
        f32x4 acc = {bias, bias, bias, bias};
#pragma unroll
        for (int kt = 0; kt < 4; ++kt)
          acc = __builtin_amdgcn_mfma_f32_16x16x32_bf16(af[mt][kt], bfr[kt], acc, 0, 0, 0);
        if (t == 0) {
#pragma unroll
          for (int r = 0; r < 4; ++r)
            Qs[(mt * 16 + quad * 4 + r) * 40 + nt * 16 + cl] = (__bf16)acc[r];
        } else if (t == 1) {
#pragma unroll
          for (int r = 0; r < 4; ++r)
            Ks[(mt * 16 + quad * 4 + r) * 40 + nt * 16 + cl] = (__bf16)acc[r];
        } else {
#pragma unroll
          for (int r = 0; r < 4; ++r)
            Vts[(nt * 16 + cl) * 72 + mt * 16 + quad * 4 + r] = (__bf16)acc[r];
        }
      }
    }
  }

  // ---- phase 2: S = Q @ K^T (all 16 tiles), mask, softmax, write P bf16 ----
  f32x4 sc4[4][4];
  {
    bf16x8 bk[4];
#pragma unroll
    for (int nt = 0; nt < 4; ++nt)
      bk[nt] = *(const bf16x8*)&Ks[(nt * 16 + cl) * 40 + quad * 8];
#pragma unroll
    for (int mt = 0; mt < 4; ++mt) {
      bf16x8 aq = *(const bf16x8*)&Qs[(mt * 16 + cl) * 40 + quad * 8];
#pragma unroll
      for (int nt = 0; nt < 4; ++nt) {
        f32x4 z = {0.f, 0.f, 0.f, 0.f};
        sc4[mt][nt] = __builtin_amdgcn_mfma_f32_16x16x32_bf16(aq, bk[nt], z, 0, 0, 0);
      }
    }
  }
  const float scale = 0.17677669529663687f;  // 1/sqrt(32)
  bool blk[4];
#pragma unroll
  for (int nt = 0; nt < 4; ++nt) blk[nt] = (fl[nt * 16 + cl] == 2);
#pragma unroll
  for (int mt = 0; mt < 4; ++mt)
#pragma unroll
    for (int nt = 0; nt < 4; ++nt)
#pragma unroll
      for (int r = 0; r < 4; ++r) {
        float v = sc4[mt][nt][r];
        sc4[mt][nt][r] = blk[nt] ? -10000.0f : v * scale;
      }
#pragma unroll
  for (int mt = 0; mt < 4; ++mt) {
#pragma unroll
    for (int r = 0; r < 4; ++r) {
      float mx = fmaxf(fmaxf(sc4[mt][0][r], sc4[mt][1][r]),
                       fmaxf(sc4[mt][2][r], sc4[mt][3][r]));
#pragma unroll
      for (int off = 1; off < 16; off <<= 1) mx = fmaxf(mx, __shfl_xor(mx, off, 64));
      float e0 = __expf(sc4[mt][0][r] - mx);
      float e1 = __expf(sc4[mt][1][r] - mx);
      float e2 = __expf(sc4[mt][2][r] - mx);
      float e3 = __expf(sc4[mt][3][r] - mx);
      float sm = (e0 + e1) + (e2 + e3);
#pragma unroll
      for (int off = 1; off < 16; off <<= 1) sm += __shfl_xor(sm, off, 64);
      float inv = 1.0f / sm;
      int row = mt * 16 + quad * 4 + r;
      Ps[row * 72 +  0 + cl] = (__bf16)(e0 * inv);
      Ps[row * 72 + 16 + cl] = (__bf16)(e1 * inv);
      Ps[row * 72 + 32 + cl] = (__bf16)(e2 * inv);
      Ps[row * 72 + 48 + cl] = (__bf16)(e3 * inv);
    }
  }

  // ---- phase 3: O = P @ V, keep in regs, then write O bf16 over Q region ----
  f32x4 oacc[4][2];
  {
    bf16x8 bv[2][2];
#pragma unroll
    for (int nt = 0; nt < 2; ++nt)
#pragma unroll
      for (int kt = 0; kt < 2; ++kt)
        bv[nt][kt] = *(const bf16x8*)&Vts[(nt * 16 + cl) * 72 + kt * 32 + quad * 8];
#pragma unroll
    for (int mt = 0; mt < 4; ++mt) {
      bf16x8 ap0 = *(const bf16x8*)&Ps[(mt * 16 + cl) * 72 + quad * 8];
      bf16x8 ap1 = *(const bf16x8*)&Ps[(mt * 16 + cl) * 72 + 32 + quad * 8];
#pragma unroll
      for (int nt = 0; nt < 2; ++nt) {
        f32x4 z = {0.f, 0.f, 0.f, 0.f};
        z = __builtin_amdgcn_mfma_f32_16x16x32_bf16(ap0, bv[nt][0], z, 0, 0, 0);
        z = __builtin_amdgcn_mfma_f32_16x16x32_bf16(ap1, bv[nt][1], z, 0, 0, 0);
        oacc[mt][nt] = z;
      }
    }
  }
#pragma unroll
  for (int mt = 0; mt < 4; ++mt)
#pragma unroll
    for (int nt = 0; nt < 2; ++nt)
#pragma unroll
      for (int r = 0; r < 4; ++r)
        Os[(mt * 16 + quad * 4 + r) * 40 + nt * 16 + cl] = (__bf16)oacc[mt][nt][r];
  __syncthreads();

  // ---- phase 4: proj = [O_h0|O_h1|O_h2|O_h3] @ projw, wave w owns 32 cols ----
  const int jw = w * 32;
#pragma unroll
  for (int mt = 0; mt < 4; ++mt) {
#pragma unroll
    for (int nt = 0; nt < 2; ++nt) {
      int col = jw + nt * 16 + cl;
      float pb = projb[col];
      f32x4 acc = {pb, pb, pb, pb};
#pragma unroll
      for (int kt = 0; kt < 4; ++kt) {
        const __bf16* op = scratch + kt * 7424;  // wave kt's O region
        bf16x8 a = *(const bf16x8*)&op[(mt * 16 + cl) * 40 + quad * 8];
        bf16x8 bb = *(const bf16x8*)&projt[(size_t)col * 128 + kt * 32 + quad * 8];
        acc = __builtin_amdgcn_mfma_f32_16x16x32_bf16(a, bb, acc, 0, 0, 0);
      }
#pragma unroll
      for (int r = 0; r < 4; ++r) {
        int row = mt * 16 + quad * 4 + r;
        if (fl[row] != 2)
          out[(size_t)srow[row] * 128 + col] = acc[r];
      }
    }
  }
}

// ---------------- MLP path: one wave per asy row, in-place on out ----------------
__global__ __launch_bounds__(256) void k_mlp(
    const float* __restrict__ x, const int* __restrict__ iw,
    const int* __restrict__ ia,
    const float* __restrict__ ln1w, const float* __restrict__ ln1b,
    const float* __restrict__ g1,
    const float* __restrict__ ln2w, const float* __restrict__ ln2b,
    const float* __restrict__ w1, const float* __restrict__ b1,
    const float* __restrict__ w2, const float* __restrict__ b2,
    const float* __restrict__ g2,
    float* __restrict__ out) {
  __shared__ float y2s[4][128];
  __shared__ float hs[4][512];
  const int tid = threadIdx.x, w = tid >> 6, lane = tid & 63;
  const int i = blockIdx.x * 4 + w;
  int s = ia[i];
  int wr = iw[s >> 6] * 64 + (s & 63);

  // xa = LN1(LN1(x_row))
  float2 xv = ((const float2*)(x + (size_t)wr * 128))[lane];
  float mean = wave_sum(xv.x + xv.y) * (1.0f / 128.0f);
  float d0 = xv.x - mean, d1 = xv.y - mean;
  float inv = rsqrtf(wave_sum(d0 * d0 + d1 * d1) * (1.0f / 128.0f) + 1e-6f);
  float lw0 = ln1w[2 * lane], lw1 = ln1w[2 * lane + 1];
  float lb0 = ln1b[2 * lane], lb1 = ln1b[2 * lane + 1];
  float y0 = d0 * inv * lw0 + lb0, y1 = d1 * inv * lw1 + lb1;
  mean = wave_sum(y0 + y1) * (1.0f / 128.0f);
  d0 = y0 - mean; d1 = y1 - mean;
  inv = rsqrtf(wave_sum(d0 * d0 + d1 * d1) * (1.0f / 128.0f) + 1e-6f);
  float xa0 = d0 * inv * lw0 + lb0, xa1 = d1 * inv * lw1 + lb1;

  // y = xa + gamma1 * o
  float2 ov = ((const float2*)(out + (size_t)wr * 128))[lane];
  float yv0 = xa0 + g1[2 * lane] * ov.x;
  float yv1 = xa1 + g1[2 * lane + 1] * ov.y;

  // y2 = LN2(y)  (wave-private slice of y2s -> no block barrier needed)
  mean = wave_sum(yv0 + yv1) * (1.0f / 128.0f);
  d0 = yv0 - mean; d1 = yv1 - mean;
  inv = rsqrtf(wave_sum(d0 * d0 + d1 * d1) * (1.0f / 128.0f) + 1e-6f);
  y2s[w][2 * lane] = d0 * inv * ln2w[2 * lane] + ln2b[2 * lane];
  y2s[w][2 * lane + 1] = d1 * inv * ln2w[2 * lane + 1] + ln2b[2 * lane + 1];

  // h = gelu(y2 @ W1 + b1): 8 independent acc chains, coalesced w1 reads
  float acc[8];
#pragma unroll
  for (int u = 0; u < 8; ++u) acc[u] = b1[lane + (u << 6)];
  for (int c = 0; c < 128; ++c) {
    float yv = y2s[w][c];
    const float* w1r = w1 + (size_t)c * 512 + lane;
#pragma unroll
    for (int u = 0; u < 8; ++u) acc[u] += yv * w1r[u << 6];
  }
#pragma unroll
  for (int u = 0; u < 8; ++u) {
    float a = acc[u];
    hs[w][lane + (u << 6)] = a * 0.5f * (1.0f + erff(a * 0.70710678118654752f));
  }

  // z = h @ W2 + b2 with 4-way ILP; final = y + gamma2 * z
  float2 bv = ((const float2*)b2)[lane];
  float s0 = bv.x, s1 = bv.y, t0 = 0.f, t1 = 0.f;
  float u0 = 0.f, u1 = 0.f, v0 = 0.f, v1 = 0.f;
  for (int c = 0; c < 512; c += 4) {
    float h0 = hs[w][c], h1 = hs[w][c + 1], h2 = hs[w][c + 2], h3 = hs[w][c + 3];
    float2 q0 = ((const float2*)(w2 + (size_t)c * 128))[lane];
    float2 q1 = ((const float2*)(w2 + (size_t)(c + 1) * 128))[lane];
    float2 q2 = ((const float2*)(w2 + (size_t)(c + 2) * 128))[lane];
    float2 q3 = ((const float2*)(w2 + (size_t)(c + 3) * 128))[lane];
    s0 += h0 * q0.x; s1 += h0 * q0.y;
    t0 += h1 * q1.x; t1 += h1 * q1.y;
    u0 += h2 * q2.x; u1 += h2 * q2.y;
    v0 += h3 * q3.x; v1 += h3 * q3.y;
  }
  float a0 = (s0 + t0) + (u0 + v0);
  float a1 = (s1 + t1) + (u1 + v1);
  float f0 = yv0 + g2[2 * lane] * a0;
  float f1 = yv1 + g2[2 * lane + 1] * a1;
  ((float2*)(out + (size_t)wr * 128))[lane] = make_float2(f0, f1);
}

extern "C" void kernel_launch(void* const* d_in, const int* in_sizes, int n_in,
                              void* d_out, int out_size, void* d_ws, size_t ws_size,
                              hipStream_t stream) {
  const float* x = (const float*)d_in[0];
  const int* iw = (const int*)d_in[1];
  const int* ip = (const int*)d_in[2];
  const int* ia = (const int*)d_in[3];
  const int* ib = (const int*)d_in[4];
  const float* ln1w = (const float*)d_in[7];
  const float* ln1b = (const float*)d_in[8];
  const float* qkvw = (const float*)d_in[9];
  const float* qkvb = (const float*)d_in[10];
  const float* projw = (const float*)d_in[11];
  const float* projb = (const float*)d_in[12];
  const float* g1 = (const float*)d_in[13];
  const float* ln2w = (const float*)d_in[14];
  const float* ln2b = (const float*)d_in[15];
  const float* w1 = (const float*)d_in[16];
  const float* b1 = (const float*)d_in[17];
  const float* w2 = (const float*)d_in[18];
  const float* b2 = (const float*)d_in[19];
  const float* g2 = (const float*)d_in[20];
  float* out = (float*)d_out;

  // ws layout: flags (MW_ B) | qkvt bf16 384x128 (98304 B) | projt bf16 128x128 (32768 B)
  unsigned char* flags = (unsigned char*)d_ws;
  __bf16* qkvt = (__bf16*)((char*)d_ws + MW_);
  __bf16* projt = (__bf16*)((char*)d_ws + MW_ + 384 * 128 * 2);

  k_set8<<<MW_ / 256, 256, 0, stream>>>(flags, MW_);
  k_scatter8<<<A_ / 256, 256, 0, stream>>>(flags, ia, 1, A_);
  k_scatter8<<<BL_ / 256, 256, 0, stream>>>(flags, ib, 2, BL_);
  k_prep<<<(384 * 128 + 128 * 128) / 256, 256, 0, stream>>>(qkvw, projw, qkvt, projt);
  k_ln_all<<<NROWS_ / 4, 256, 0, stream>>>(x, ln1w, ln1b, out);
  k_attn<<<M_, 256, 0, stream>>>(x, iw, ip, flags, ln1w, ln1b, qkvt, qkvb,
                                 projt, projb, out);
  k_mlp<<<A_ / 4, 256, 0, stream>>>(x, iw, ia, ln1w, ln1b, g1, ln2w, ln2b,
                                    w1, b1, w2, b2, g2, out);
}